// Round 10
// baseline (419.049 us; speedup 1.0000x reference)
//
#include <hip/hip_runtime.h>

// GCLayer: out[dst] += (X @ W_k)[src] over 4 edge sets.
// Round 10: coarser partition buckets (512 nodes, EPB=16384 -> 334B scatter
// runs), fused prep_w+conv_x, gg inner unroll 16 (4 uint4 in flight).
// CSR build has ZERO global atomics. 7 dispatches.
// Assumes n <= 131072 (src packed in 17 bits; problem fixed at N=100000).

#define H 128
#define BSH 9                    // bucket shift: 512 nodes per bucket
#define BNODES (1 << BSH)
#define SEGB (BNODES * 4)        // 2048 segments per bucket
#define EPB 16384                // edges per partition block (256 thr x 64)

typedef __bf16 bf16x8 __attribute__((ext_vector_type(8)));
typedef float f32x4 __attribute__((ext_vector_type(4)));

static __device__ __forceinline__ ushort f2bf(float f) {
  union { float f; uint u; } v; v.f = f;
  uint r = (v.u + 0x7FFFu + ((v.u >> 16) & 1u)) >> 16;
  return (ushort)r;
}
static __device__ __forceinline__ float bflo(uint u) {
  union { uint u; float f; } v; v.u = u << 16; return v.f;
}
static __device__ __forceinline__ float bfhi(uint u) {
  union { uint u; float f; } v; v.u = u & 0xFFFF0000u; return v.f;
}

// ---------------------------------------------------------------------------
// Fused: Xb = bf16(X) AND Wt[k][c][kk] = bf16(W_k[kk][c])
// ---------------------------------------------------------------------------
__global__ __launch_bounds__(256) void conv_prep(const float4* __restrict__ X4,
                                                 uint2* __restrict__ Xb2, int m,
                                                 const float* __restrict__ W0,
                                                 const float* __restrict__ W1,
                                                 const float* __restrict__ W2,
                                                 const float* __restrict__ W3,
                                                 ushort* __restrict__ Wt) {
  int i = blockIdx.x * 256 + threadIdx.x;
  if (i < m) {
    float4 v = X4[i];
    uint2 p;
    p.x = (uint)f2bf(v.x) | ((uint)f2bf(v.y) << 16);
    p.y = (uint)f2bf(v.z) | ((uint)f2bf(v.w) << 16);
    Xb2[i] = p;
  }
  if (i < 65536) {
    int kk = i & 127;
    int c = (i >> 7) & 127;
    int k = i >> 14;
    const float* W = (k == 0) ? W0 : (k == 1) ? W1 : (k == 2) ? W2 : W3;
    Wt[i] = f2bf(W[kk * 128 + c]);
  }
}

// ---------------------------------------------------------------------------
static __device__ __forceinline__ void fetch_edge(
    int gid, int c1, int c2, int c3,
    const int* d0, const int* d1, const int* d2, const int* d3,
    const int* s0, const int* s1, const int* s2, const int* s3,
    int& dst, int& src, int& k) {
  int i;
  const int *dp, *sp;
  if (gid < c1)      { k = 0; i = gid;      dp = d0; sp = s0; }
  else if (gid < c2) { k = 1; i = gid - c1; dp = d1; sp = s1; }
  else if (gid < c3) { k = 2; i = gid - c2; dp = d2; sp = s2; }
  else               { k = 3; i = gid - c3; dp = d3; sp = s3; }
  dst = dp[i];
  src = sp[i];
}

// ---------------------------------------------------------------------------
// Pass A1: per-block bucket histogram (bucket = dst >> BSH).
// ---------------------------------------------------------------------------
__global__ __launch_bounds__(256) void part_count(
    const int* __restrict__ d0, const int* __restrict__ d1,
    const int* __restrict__ d2, const int* __restrict__ d3,
    int c1, int c2, int c3, int tot, int nbin, int* __restrict__ hb) {
  __shared__ int lh[512];
  for (int i = threadIdx.x; i < nbin; i += 256) lh[i] = 0;
  __syncthreads();
  int base = blockIdx.x * EPB;
#pragma unroll 8
  for (int u = 0; u < EPB / 256; ++u) {
    int gid = base + u * 256 + threadIdx.x;
    if (gid < tot) {
      int i;
      const int* dp;
      if (gid < c1)      { i = gid;      dp = d0; }
      else if (gid < c2) { i = gid - c1; dp = d1; }
      else if (gid < c3) { i = gid - c2; dp = d2; }
      else               { i = gid - c3; dp = d3; }
      atomicAdd(&lh[dp[i] >> BSH], 1);
    }
  }
  __syncthreads();
  int* row = hb + (size_t)blockIdx.x * nbin;
  for (int i = threadIdx.x; i < nbin; i += 256) row[i] = lh[i];
}

// ---------------------------------------------------------------------------
// Pass A2a: per-bucket exclusive prefix over blocks.
// ---------------------------------------------------------------------------
__global__ __launch_bounds__(256) void part_scanA(int* __restrict__ hb,
                                                  int nblk, int nbin,
                                                  int* __restrict__ btot) {
  __shared__ int ws4[4];
  const int bin = blockIdx.x;
  const int t = threadIdx.x, lane = t & 63, wid = t >> 6;
  const int C = (nblk + 255) / 256;
  int b0 = t * C;
  int b1 = min(b0 + C, nblk);
  int s = 0;
  for (int b = b0; b < b1; ++b) s += hb[(size_t)b * nbin + bin];
  int incl = s;
#pragma unroll
  for (int d = 1; d < 64; d <<= 1) {
    int x = __shfl_up(incl, d, 64);
    if (lane >= d) incl += x;
  }
  if (lane == 63) ws4[wid] = incl;
  __syncthreads();
  if (t == 0) {
    int run = 0;
#pragma unroll
    for (int i = 0; i < 4; ++i) { int v = ws4[i]; ws4[i] = run; run += v; }
  }
  __syncthreads();
  int run = ws4[wid] + (incl - s);
  for (int b = b0; b < b1; ++b) {
    int v = hb[(size_t)b * nbin + bin];
    hb[(size_t)b * nbin + bin] = run;
    run += v;
  }
  if (t == 255) btot[bin] = run;
}

// ---------------------------------------------------------------------------
// Pass A2b: exclusive scan of bucket totals (nbin <= 512).
// ---------------------------------------------------------------------------
__global__ __launch_bounds__(512) void part_scanB(const int* __restrict__ btot,
                                                  int* __restrict__ binbase,
                                                  int nbin) {
  __shared__ int ws8[8];
  const int t = threadIdx.x, lane = t & 63, wid = t >> 6;
  int v = (t < nbin) ? btot[t] : 0;
  int incl = v;
#pragma unroll
  for (int d = 1; d < 64; d <<= 1) {
    int x = __shfl_up(incl, d, 64);
    if (lane >= d) incl += x;
  }
  if (lane == 63) ws8[wid] = incl;
  __syncthreads();
  if (t == 0) {
    int run = 0;
#pragma unroll
    for (int i = 0; i < 8; ++i) { int v2 = ws8[i]; ws8[i] = run; run += v2; }
  }
  __syncthreads();
  int excl = ws8[wid] + (incl - v);
  if (t < nbin) binbase[t] = excl;
  if (t == nbin - 1) binbase[nbin] = excl + v;
}

// ---------------------------------------------------------------------------
// Pass A3: scatter edges into bucket-partitioned array (334B avg runs).
// packed entry = src | (seg_local << 17), seg_local = (dst & 511)*4 + k.
// ---------------------------------------------------------------------------
__global__ __launch_bounds__(256) void part_scatter(
    const int* __restrict__ d0, const int* __restrict__ d1,
    const int* __restrict__ d2, const int* __restrict__ d3,
    const int* __restrict__ s0, const int* __restrict__ s1,
    const int* __restrict__ s2, const int* __restrict__ s3,
    int c1, int c2, int c3, int tot, int nbin,
    const int* __restrict__ hb, const int* __restrict__ binbase,
    uint* __restrict__ part) {
  __shared__ int cur[512];
  const int* row = hb + (size_t)blockIdx.x * nbin;
  for (int i = threadIdx.x; i < nbin; i += 256) cur[i] = binbase[i] + row[i];
  __syncthreads();
  int base = blockIdx.x * EPB;
#pragma unroll 8
  for (int u = 0; u < EPB / 256; ++u) {
    int gid = base + u * 256 + threadIdx.x;
    if (gid < tot) {
      int dst, src, k;
      fetch_edge(gid, c1, c2, c3, d0, d1, d2, d3, s0, s1, s2, s3, dst, src, k);
      int pos = atomicAdd(&cur[dst >> BSH], 1);
      part[pos] = (uint)src | ((uint)(((dst & (BNODES - 1)) << 2) | k) << 17);
    }
  }
}

// ---------------------------------------------------------------------------
// Pass B: one block per bucket (1024 thr). LDS histogram over SEGB=2048
// segments (2 per thread in the scan), write rp4, rank via LDS cursors.
// ---------------------------------------------------------------------------
__global__ __launch_bounds__(1024) void build_bucket(
    const uint* __restrict__ part, const int* __restrict__ binbase,
    int* __restrict__ rp4, int* __restrict__ col_idx) {
  __shared__ int lh[SEGB];
  __shared__ int ws16[16];
  const int b = blockIdx.x;
  const int beg = binbase[b], end = binbase[b + 1];
  const int t = threadIdx.x, lane = t & 63, wid = t >> 6;

  lh[t] = 0;
  lh[t + 1024] = 0;
  __syncthreads();
  for (int i = beg + t; i < end; i += 1024)
    atomicAdd(&lh[part[i] >> 17], 1);
  __syncthreads();

  // scan 2048 entries, 2 per thread
  int v0 = lh[2 * t], v1 = lh[2 * t + 1];
  int s = v0 + v1;
  int incl = s;
#pragma unroll
  for (int d = 1; d < 64; d <<= 1) {
    int x = __shfl_up(incl, d, 64);
    if (lane >= d) incl += x;
  }
  if (lane == 63) ws16[wid] = incl;
  __syncthreads();
  if (t == 0) {
    int run = 0;
#pragma unroll
    for (int i = 0; i < 16; ++i) { int w = ws16[i]; ws16[i] = run; run += w; }
  }
  __syncthreads();
  int excl = beg + ws16[wid] + (incl - s);
  lh[2 * t] = excl;
  lh[2 * t + 1] = excl + v0;

  int gseg = b * SEGB + 2 * t;
  rp4[gseg] = excl;
  rp4[gseg + 1] = excl + v0;
  __syncthreads();

  for (int i = beg + t; i < end; i += 1024) {
    uint e = part[i];
    int pos = atomicAdd(&lh[e >> 17], 1);
    col_idx[pos] = (int)(e & 0x1FFFFu);
  }
}

// ---------------------------------------------------------------------------
// Fused gather + GEMM. Block: 256 threads = 4 waves; 16 nodes/block.
// Gather: 4 edges per wave-load (uint4 per lane, 16-lane groups); indices
// preloaded to VGPRs, distributed via __shfl; 16-edge unroll (4 loads in
// flight); cross-group __shfl_xor reduce; lanes 0-15 store packed row.
// ---------------------------------------------------------------------------
#define ACC8(u)                                                       \
  do {                                                                \
    a0 += bflo((u).x); a1 += bfhi((u).x);                             \
    a2 += bflo((u).y); a3 += bfhi((u).y);                             \
    a4 += bflo((u).z); a5 += bfhi((u).z);                             \
    a6 += bflo((u).w); a7 += bfhi((u).w);                             \
  } while (0)

__global__ __launch_bounds__(256, 8) void gg(const uint* __restrict__ Xb,
                                             const int* __restrict__ rp4,
                                             const int* __restrict__ col_idx,
                                             const ushort* __restrict__ Wt,
                                             float* __restrict__ out, int n) {
  __shared__ uint sS[16][258];   // pad 2 -> bank stride 2 (free 2-way)

  const int node0 = blockIdx.x * 16;
  const int wave = threadIdx.x >> 6;
  const int lane = threadIdx.x & 63;
  const int g = lane >> 4;          // edge sub-group 0..3
  const int qb = (lane & 15) * 4;   // uint offset within row

  // ---- gather phase ----
#pragma unroll 1
  for (int i = 0; i < 4; ++i) {
    int local = wave * 4 + i;
    int node = node0 + local;
    if (node < n) {
      const int4 rpv = *(const int4*)(rp4 + (size_t)node * 4);
      const int rpE = rp4[(size_t)node * 4 + 4];
      int pe0 = (rpv.x + lane < rpv.y) ? col_idx[rpv.x + lane] : 0;
      int pe1 = (rpv.y + lane < rpv.z) ? col_idx[rpv.y + lane] : 0;
      int pe2 = (rpv.z + lane < rpv.w) ? col_idx[rpv.z + lane] : 0;
      int pe3 = (rpv.w + lane < rpE)   ? col_idx[rpv.w + lane] : 0;
#pragma unroll
      for (int k = 0; k < 4; ++k) {
        int beg = (k == 0) ? rpv.x : (k == 1) ? rpv.y : (k == 2) ? rpv.z : rpv.w;
        int end = (k == 0) ? rpv.y : (k == 1) ? rpv.z : (k == 2) ? rpv.w : rpE;
        int pe  = (k == 0) ? pe0   : (k == 1) ? pe1   : (k == 2) ? pe2   : pe3;
        int len = end - beg;
        int m = (len > 64) ? 64 : len;
        float a0 = 0.f, a1 = 0.f, a2 = 0.f, a3 = 0.f;
        float a4 = 0.f, a5 = 0.f, a6 = 0.f, a7 = 0.f;
        int s = 0;
        for (; s + 16 <= m; s += 16) {        // 16 edges, 4 loads in flight
          int ea = __shfl(pe, s + g, 64);
          int eb = __shfl(pe, s + 4 + g, 64);
          int ec = __shfl(pe, s + 8 + g, 64);
          int ed = __shfl(pe, s + 12 + g, 64);
          uint4 ua = *(const uint4*)&Xb[(size_t)ea * 64 + qb];
          uint4 ub = *(const uint4*)&Xb[(size_t)eb * 64 + qb];
          uint4 uc = *(const uint4*)&Xb[(size_t)ec * 64 + qb];
          uint4 ud = *(const uint4*)&Xb[(size_t)ed * 64 + qb];
          ACC8(ua); ACC8(ub); ACC8(uc); ACC8(ud);
        }
        for (; s + 8 <= m; s += 8) {
          int ea = __shfl(pe, s + g, 64);
          int eb = __shfl(pe, s + 4 + g, 64);
          uint4 ua = *(const uint4*)&Xb[(size_t)ea * 64 + qb];
          uint4 ub = *(const uint4*)&Xb[(size_t)eb * 64 + qb];
          ACC8(ua); ACC8(ub);
        }
        for (; s < m; s += 4) {
          int li = s + g;
          int e = __shfl(pe, li, 64);
          if (li < m) {
            uint4 u = *(const uint4*)&Xb[(size_t)e * 64 + qb];
            ACC8(u);
          }
        }
        if (len > 64) {                        // rare overflow path
          for (int j = beg + 64; j < end; j += 4) {
            int li = j + g;
            if (li < end) {
              int e = col_idx[li];
              uint4 u = *(const uint4*)&Xb[(size_t)e * 64 + qb];
              ACC8(u);
            }
          }
        }
        a0 += __shfl_xor(a0, 16, 64); a0 += __shfl_xor(a0, 32, 64);
        a1 += __shfl_xor(a1, 16, 64); a1 += __shfl_xor(a1, 32, 64);
        a2 += __shfl_xor(a2, 16, 64); a2 += __shfl_xor(a2, 32, 64);
        a3 += __shfl_xor(a3, 16, 64); a3 += __shfl_xor(a3, 32, 64);
        a4 += __shfl_xor(a4, 16, 64); a4 += __shfl_xor(a4, 32, 64);
        a5 += __shfl_xor(a5, 16, 64); a5 += __shfl_xor(a5, 32, 64);
        a6 += __shfl_xor(a6, 16, 64); a6 += __shfl_xor(a6, 32, 64);
        a7 += __shfl_xor(a7, 16, 64); a7 += __shfl_xor(a7, 32, 64);
        if (lane < 16) {
          uint* drow = &sS[local][k * 64 + qb];
          drow[0] = (uint)f2bf(a0) | ((uint)f2bf(a1) << 16);
          drow[1] = (uint)f2bf(a2) | ((uint)f2bf(a3) << 16);
          drow[2] = (uint)f2bf(a4) | ((uint)f2bf(a5) << 16);
          drow[3] = (uint)f2bf(a6) | ((uint)f2bf(a7) << 16);
        }
      }
    } else {
#pragma unroll
      for (int k = 0; k < 4; ++k) sS[local][k * 64 + lane] = 0u;
    }
  }
  __syncthreads();

  // ---- GEMM phase ----
  const ushort* sSu = (const ushort*)&sS[0][0];   // row stride 516 ushorts
  const int lr = lane & 15;
  const int lg = lane >> 4;
  const int cf0 = wave * 2;

  f32x4 acc0 = (f32x4)0.f, acc1 = (f32x4)0.f;

#pragma unroll
  for (int kc = 0; kc < 4; ++kc) {
#pragma unroll
    for (int k4 = 0; k4 < 4; ++k4) {
      bf16x8 a = *(const bf16x8*)&sSu[lr * 516 + kc * 128 + k4 * 32 + lg * 8];
      bf16x8 b0 = *(const bf16x8*)&Wt[kc * 16384 + (cf0 * 16 + lr) * 128 + k4 * 32 + lg * 8];
      bf16x8 b1 = *(const bf16x8*)&Wt[kc * 16384 + ((cf0 + 1) * 16 + lr) * 128 + k4 * 32 + lg * 8];
      acc0 = __builtin_amdgcn_mfma_f32_16x16x32_bf16(a, b0, acc0, 0, 0, 0);
      acc1 = __builtin_amdgcn_mfma_f32_16x16x32_bf16(a, b1, acc1, 0, 0, 0);
    }
  }

#pragma unroll
  for (int r = 0; r < 4; ++r) {
    int row = node0 + lg * 4 + r;
    if (row < n) {
      out[(size_t)row * H + cf0 * 16 + lr] = acc0[r];
      out[(size_t)row * H + (cf0 + 1) * 16 + lr] = acc1[r];
    }
  }
}

// ---------------------------------------------------------------------------
extern "C" void kernel_launch(void* const* d_in, const int* in_sizes, int n_in,
                              void* d_out, int out_size, void* d_ws, size_t ws_size,
                              hipStream_t stream) {
  const float* X = (const float*)d_in[0];
  const int* edges[4] = {(const int*)d_in[1], (const int*)d_in[2],
                         (const int*)d_in[3], (const int*)d_in[4]};
  const float* Wk[4] = {(const float*)d_in[5], (const float*)d_in[6],
                        (const float*)d_in[7], (const float*)d_in[8]};
  float* out = (float*)d_out;

  int n = in_sizes[0] / H;
  int nE[4];
  int tot = 0;
  for (int k = 0; k < 4; ++k) {
    nE[k] = in_sizes[1 + k] / 2;
    tot += nE[k];
  }
  int c1 = nE[0], c2 = c1 + nE[1], c3 = c2 + nE[2];
  int nbin = (n + BNODES - 1) >> BSH;   // dst buckets
  int nblk = (tot + EPB - 1) / EPB;     // partition blocks

  // workspace layout
  char* ws = (char*)d_ws;
  size_t off = 0;
  auto take = [&](size_t bytes) -> char* {
    char* p = ws + off;
    off = (off + bytes + 255) & ~(size_t)255;
    return p;
  };
  ushort* Wt = (ushort*)take(4 * 128 * 128 * sizeof(ushort));
  uint* Xb = (uint*)take((size_t)n * H * sizeof(ushort));
  int* hb = (int*)take((size_t)nblk * nbin * sizeof(int));
  int* btot = (int*)take((size_t)nbin * sizeof(int));
  int* binbase = (int*)take((size_t)(nbin + 1) * sizeof(int));
  int* rp4 = (int*)take(((size_t)nbin * SEGB + 1) * sizeof(int));
  uint* part = (uint*)take((size_t)tot * sizeof(uint));
  int* col_idx = (int*)take((size_t)tot * sizeof(int));

  const int* s0 = edges[0];
  const int* d0 = edges[0] + nE[0];
  const int* s1 = edges[1];
  const int* d1 = edges[1] + nE[1];
  const int* s2 = edges[2];
  const int* d2 = edges[2] + nE[2];
  const int* s3 = edges[3];
  const int* d3 = edges[3] + nE[3];

  conv_prep<<<(n * 32 + 255) / 256, 256, 0, stream>>>(
      (const float4*)X, (uint2*)Xb, n * 32, Wk[0], Wk[1], Wk[2], Wk[3], Wt);

  part_count<<<nblk, 256, 0, stream>>>(d0, d1, d2, d3, c1, c2, c3, tot, nbin, hb);
  part_scanA<<<nbin, 256, 0, stream>>>(hb, nblk, nbin, btot);
  part_scanB<<<1, 512, 0, stream>>>(btot, binbase, nbin);
  part_scatter<<<nblk, 256, 0, stream>>>(d0, d1, d2, d3, s0, s1, s2, s3,
                                         c1, c2, c3, tot, nbin, hb, binbase, part);
  build_bucket<<<nbin, 1024, 0, stream>>>(part, binbase, rp4, col_idx);

  gg<<<(n + 15) / 16, 256, 0, stream>>>(Xb, rp4, col_idx, Wt, out, n);
}

// Round 11
// 395.150 us; speedup vs baseline: 1.0605x; 1.0605x over previous
//
#include <hip/hip_runtime.h>

// GCLayer: out[dst] += (X @ W_k)[src] over 4 edge sets.
// Round 11: gg hoists ALL per-node index preloads (4x rpv/rpE + 16x pe) to
// kernel top -> one batch of independent loads instead of 4 serial chains.
// 8-edge inner unroll (measured best). launch_bounds (256,6) to avoid spill.
// CSR build (two-level LDS partition, zero global atomics) unchanged.
// Assumes n <= 131072 (src packed in 17 bits; problem fixed at N=100000).

#define H 128
#define BSH 9                    // bucket shift: 512 nodes per bucket
#define BNODES (1 << BSH)
#define SEGB (BNODES * 4)        // 2048 segments per bucket
#define EPB 16384                // edges per partition block (256 thr x 64)

typedef __bf16 bf16x8 __attribute__((ext_vector_type(8)));
typedef float f32x4 __attribute__((ext_vector_type(4)));

static __device__ __forceinline__ ushort f2bf(float f) {
  union { float f; uint u; } v; v.f = f;
  uint r = (v.u + 0x7FFFu + ((v.u >> 16) & 1u)) >> 16;
  return (ushort)r;
}
static __device__ __forceinline__ float bflo(uint u) {
  union { uint u; float f; } v; v.u = u << 16; return v.f;
}
static __device__ __forceinline__ float bfhi(uint u) {
  union { uint u; float f; } v; v.u = u & 0xFFFF0000u; return v.f;
}

// ---------------------------------------------------------------------------
// Fused: Xb = bf16(X) AND Wt[k][c][kk] = bf16(W_k[kk][c])
// ---------------------------------------------------------------------------
__global__ __launch_bounds__(256) void conv_prep(const float4* __restrict__ X4,
                                                 uint2* __restrict__ Xb2, int m,
                                                 const float* __restrict__ W0,
                                                 const float* __restrict__ W1,
                                                 const float* __restrict__ W2,
                                                 const float* __restrict__ W3,
                                                 ushort* __restrict__ Wt) {
  int i = blockIdx.x * 256 + threadIdx.x;
  if (i < m) {
    float4 v = X4[i];
    uint2 p;
    p.x = (uint)f2bf(v.x) | ((uint)f2bf(v.y) << 16);
    p.y = (uint)f2bf(v.z) | ((uint)f2bf(v.w) << 16);
    Xb2[i] = p;
  }
  if (i < 65536) {
    int kk = i & 127;
    int c = (i >> 7) & 127;
    int k = i >> 14;
    const float* W = (k == 0) ? W0 : (k == 1) ? W1 : (k == 2) ? W2 : W3;
    Wt[i] = f2bf(W[kk * 128 + c]);
  }
}

// ---------------------------------------------------------------------------
static __device__ __forceinline__ void fetch_edge(
    int gid, int c1, int c2, int c3,
    const int* d0, const int* d1, const int* d2, const int* d3,
    const int* s0, const int* s1, const int* s2, const int* s3,
    int& dst, int& src, int& k) {
  int i;
  const int *dp, *sp;
  if (gid < c1)      { k = 0; i = gid;      dp = d0; sp = s0; }
  else if (gid < c2) { k = 1; i = gid - c1; dp = d1; sp = s1; }
  else if (gid < c3) { k = 2; i = gid - c2; dp = d2; sp = s2; }
  else               { k = 3; i = gid - c3; dp = d3; sp = s3; }
  dst = dp[i];
  src = sp[i];
}

// ---------------------------------------------------------------------------
__global__ __launch_bounds__(256) void part_count(
    const int* __restrict__ d0, const int* __restrict__ d1,
    const int* __restrict__ d2, const int* __restrict__ d3,
    int c1, int c2, int c3, int tot, int nbin, int* __restrict__ hb) {
  __shared__ int lh[512];
  for (int i = threadIdx.x; i < nbin; i += 256) lh[i] = 0;
  __syncthreads();
  int base = blockIdx.x * EPB;
#pragma unroll 8
  for (int u = 0; u < EPB / 256; ++u) {
    int gid = base + u * 256 + threadIdx.x;
    if (gid < tot) {
      int i;
      const int* dp;
      if (gid < c1)      { i = gid;      dp = d0; }
      else if (gid < c2) { i = gid - c1; dp = d1; }
      else if (gid < c3) { i = gid - c2; dp = d2; }
      else               { i = gid - c3; dp = d3; }
      atomicAdd(&lh[dp[i] >> BSH], 1);
    }
  }
  __syncthreads();
  int* row = hb + (size_t)blockIdx.x * nbin;
  for (int i = threadIdx.x; i < nbin; i += 256) row[i] = lh[i];
}

__global__ __launch_bounds__(256) void part_scanA(int* __restrict__ hb,
                                                  int nblk, int nbin,
                                                  int* __restrict__ btot) {
  __shared__ int ws4[4];
  const int bin = blockIdx.x;
  const int t = threadIdx.x, lane = t & 63, wid = t >> 6;
  const int C = (nblk + 255) / 256;
  int b0 = t * C;
  int b1 = min(b0 + C, nblk);
  int s = 0;
  for (int b = b0; b < b1; ++b) s += hb[(size_t)b * nbin + bin];
  int incl = s;
#pragma unroll
  for (int d = 1; d < 64; d <<= 1) {
    int x = __shfl_up(incl, d, 64);
    if (lane >= d) incl += x;
  }
  if (lane == 63) ws4[wid] = incl;
  __syncthreads();
  if (t == 0) {
    int run = 0;
#pragma unroll
    for (int i = 0; i < 4; ++i) { int v = ws4[i]; ws4[i] = run; run += v; }
  }
  __syncthreads();
  int run = ws4[wid] + (incl - s);
  for (int b = b0; b < b1; ++b) {
    int v = hb[(size_t)b * nbin + bin];
    hb[(size_t)b * nbin + bin] = run;
    run += v;
  }
  if (t == 255) btot[bin] = run;
}

__global__ __launch_bounds__(512) void part_scanB(const int* __restrict__ btot,
                                                  int* __restrict__ binbase,
                                                  int nbin) {
  __shared__ int ws8[8];
  const int t = threadIdx.x, lane = t & 63, wid = t >> 6;
  int v = (t < nbin) ? btot[t] : 0;
  int incl = v;
#pragma unroll
  for (int d = 1; d < 64; d <<= 1) {
    int x = __shfl_up(incl, d, 64);
    if (lane >= d) incl += x;
  }
  if (lane == 63) ws8[wid] = incl;
  __syncthreads();
  if (t == 0) {
    int run = 0;
#pragma unroll
    for (int i = 0; i < 8; ++i) { int v2 = ws8[i]; ws8[i] = run; run += v2; }
  }
  __syncthreads();
  int excl = ws8[wid] + (incl - v);
  if (t < nbin) binbase[t] = excl;
  if (t == nbin - 1) binbase[nbin] = excl + v;
}

__global__ __launch_bounds__(256) void part_scatter(
    const int* __restrict__ d0, const int* __restrict__ d1,
    const int* __restrict__ d2, const int* __restrict__ d3,
    const int* __restrict__ s0, const int* __restrict__ s1,
    const int* __restrict__ s2, const int* __restrict__ s3,
    int c1, int c2, int c3, int tot, int nbin,
    const int* __restrict__ hb, const int* __restrict__ binbase,
    uint* __restrict__ part) {
  __shared__ int cur[512];
  const int* row = hb + (size_t)blockIdx.x * nbin;
  for (int i = threadIdx.x; i < nbin; i += 256) cur[i] = binbase[i] + row[i];
  __syncthreads();
  int base = blockIdx.x * EPB;
#pragma unroll 8
  for (int u = 0; u < EPB / 256; ++u) {
    int gid = base + u * 256 + threadIdx.x;
    if (gid < tot) {
      int dst, src, k;
      fetch_edge(gid, c1, c2, c3, d0, d1, d2, d3, s0, s1, s2, s3, dst, src, k);
      int pos = atomicAdd(&cur[dst >> BSH], 1);
      part[pos] = (uint)src | ((uint)(((dst & (BNODES - 1)) << 2) | k) << 17);
    }
  }
}

__global__ __launch_bounds__(1024) void build_bucket(
    const uint* __restrict__ part, const int* __restrict__ binbase,
    int* __restrict__ rp4, int* __restrict__ col_idx) {
  __shared__ int lh[SEGB];
  __shared__ int ws16[16];
  const int b = blockIdx.x;
  const int beg = binbase[b], end = binbase[b + 1];
  const int t = threadIdx.x, lane = t & 63, wid = t >> 6;

  lh[t] = 0;
  lh[t + 1024] = 0;
  __syncthreads();
  for (int i = beg + t; i < end; i += 1024)
    atomicAdd(&lh[part[i] >> 17], 1);
  __syncthreads();

  int v0 = lh[2 * t], v1 = lh[2 * t + 1];
  int s = v0 + v1;
  int incl = s;
#pragma unroll
  for (int d = 1; d < 64; d <<= 1) {
    int x = __shfl_up(incl, d, 64);
    if (lane >= d) incl += x;
  }
  if (lane == 63) ws16[wid] = incl;
  __syncthreads();
  if (t == 0) {
    int run = 0;
#pragma unroll
    for (int i = 0; i < 16; ++i) { int w = ws16[i]; ws16[i] = run; run += w; }
  }
  __syncthreads();
  int excl = beg + ws16[wid] + (incl - s);
  lh[2 * t] = excl;
  lh[2 * t + 1] = excl + v0;

  int gseg = b * SEGB + 2 * t;
  rp4[gseg] = excl;
  rp4[gseg + 1] = excl + v0;
  __syncthreads();

  for (int i = beg + t; i < end; i += 1024) {
    uint e = part[i];
    int pos = atomicAdd(&lh[e >> 17], 1);
    col_idx[pos] = (int)(e & 0x1FFFFu);
  }
}

// ---------------------------------------------------------------------------
// Fused gather + GEMM. Block: 256 threads = 4 waves; 16 nodes/block.
// All 4 nodes' rp/col_idx preloads hoisted to kernel top (24 independent
// loads in flight before any gather math). Gather: 4 edge-rows per
// wave-load (uint4/lane, 16-lane groups), 8-edge unroll, __shfl_xor reduce.
// ---------------------------------------------------------------------------
#define ACC8(u)                                                       \
  do {                                                                \
    a0 += bflo((u).x); a1 += bfhi((u).x);                             \
    a2 += bflo((u).y); a3 += bfhi((u).y);                             \
    a4 += bflo((u).z); a5 += bfhi((u).z);                             \
    a6 += bflo((u).w); a7 += bfhi((u).w);                             \
  } while (0)

__global__ __launch_bounds__(256, 6) void gg(const uint* __restrict__ Xb,
                                             const int* __restrict__ rp4,
                                             const int* __restrict__ col_idx,
                                             const ushort* __restrict__ Wt,
                                             float* __restrict__ out, int n) {
  __shared__ uint sS[16][258];   // pad 2 -> bank stride 2 (free 2-way)

  const int node0 = blockIdx.x * 16;
  const int wave = threadIdx.x >> 6;
  const int lane = threadIdx.x & 63;
  const int g = lane >> 4;          // edge sub-group 0..3
  const int qb = (lane & 15) * 4;   // uint offset within row

  // ---- hoisted index preloads for this wave's 4 nodes ----
  // rp4 is valid for all node < nbin*BNODES >= grid coverage; empty segments
  // have beg==end, so no node-validity guard is needed here.
  int4 rpv[4];
  int rpE[4];
#pragma unroll
  for (int i = 0; i < 4; ++i) {
    int node = node0 + wave * 4 + i;
    rpv[i] = *(const int4*)(rp4 + (size_t)node * 4);
    rpE[i] = rp4[(size_t)node * 4 + 4];
  }
  int pe[4][4];
#pragma unroll
  for (int i = 0; i < 4; ++i) {
    pe[i][0] = (rpv[i].x + lane < rpv[i].y) ? col_idx[rpv[i].x + lane] : 0;
    pe[i][1] = (rpv[i].y + lane < rpv[i].z) ? col_idx[rpv[i].y + lane] : 0;
    pe[i][2] = (rpv[i].z + lane < rpv[i].w) ? col_idx[rpv[i].z + lane] : 0;
    pe[i][3] = (rpv[i].w + lane < rpE[i])   ? col_idx[rpv[i].w + lane] : 0;
  }

  // ---- gather phase ----
#pragma unroll
  for (int i = 0; i < 4; ++i) {
    int local = wave * 4 + i;
#pragma unroll
    for (int k = 0; k < 4; ++k) {
      int beg = (k == 0) ? rpv[i].x : (k == 1) ? rpv[i].y
              : (k == 2) ? rpv[i].z : rpv[i].w;
      int end = (k == 0) ? rpv[i].y : (k == 1) ? rpv[i].z
              : (k == 2) ? rpv[i].w : rpE[i];
      int p = pe[i][k];
      int len = end - beg;
      int m = (len > 64) ? 64 : len;
      float a0 = 0.f, a1 = 0.f, a2 = 0.f, a3 = 0.f;
      float a4 = 0.f, a5 = 0.f, a6 = 0.f, a7 = 0.f;
      int s = 0;
      for (; s + 8 <= m; s += 8) {          // 8 edges (2 wave-loads) per iter
        int ea = __shfl(p, s + g, 64);
        int eb = __shfl(p, s + 4 + g, 64);
        uint4 ua = *(const uint4*)&Xb[(size_t)ea * 64 + qb];
        uint4 ub = *(const uint4*)&Xb[(size_t)eb * 64 + qb];
        ACC8(ua);
        ACC8(ub);
      }
      for (; s < m; s += 4) {               // tail, 4 edges
        int li = s + g;
        int e = __shfl(p, li, 64);
        if (li < m) {
          uint4 u = *(const uint4*)&Xb[(size_t)e * 64 + qb];
          ACC8(u);
        }
      }
      if (len > 64) {                        // rare overflow path
        for (int j = beg + 64; j < end; j += 4) {
          int li = j + g;
          if (li < end) {
            int e = col_idx[li];
            uint4 u = *(const uint4*)&Xb[(size_t)e * 64 + qb];
            ACC8(u);
          }
        }
      }
      a0 += __shfl_xor(a0, 16, 64); a0 += __shfl_xor(a0, 32, 64);
      a1 += __shfl_xor(a1, 16, 64); a1 += __shfl_xor(a1, 32, 64);
      a2 += __shfl_xor(a2, 16, 64); a2 += __shfl_xor(a2, 32, 64);
      a3 += __shfl_xor(a3, 16, 64); a3 += __shfl_xor(a3, 32, 64);
      a4 += __shfl_xor(a4, 16, 64); a4 += __shfl_xor(a4, 32, 64);
      a5 += __shfl_xor(a5, 16, 64); a5 += __shfl_xor(a5, 32, 64);
      a6 += __shfl_xor(a6, 16, 64); a6 += __shfl_xor(a6, 32, 64);
      a7 += __shfl_xor(a7, 16, 64); a7 += __shfl_xor(a7, 32, 64);
      if (lane < 16) {
        uint* drow = &sS[local][k * 64 + qb];
        drow[0] = (uint)f2bf(a0) | ((uint)f2bf(a1) << 16);
        drow[1] = (uint)f2bf(a2) | ((uint)f2bf(a3) << 16);
        drow[2] = (uint)f2bf(a4) | ((uint)f2bf(a5) << 16);
        drow[3] = (uint)f2bf(a6) | ((uint)f2bf(a7) << 16);
      }
    }
  }
  __syncthreads();

  // ---- GEMM phase ----
  const ushort* sSu = (const ushort*)&sS[0][0];   // row stride 516 ushorts
  const int lr = lane & 15;
  const int lg = lane >> 4;
  const int cf0 = wave * 2;

  f32x4 acc0 = (f32x4)0.f, acc1 = (f32x4)0.f;

#pragma unroll
  for (int kc = 0; kc < 4; ++kc) {
#pragma unroll
    for (int k4 = 0; k4 < 4; ++k4) {
      bf16x8 a = *(const bf16x8*)&sSu[lr * 516 + kc * 128 + k4 * 32 + lg * 8];
      bf16x8 b0 = *(const bf16x8*)&Wt[kc * 16384 + (cf0 * 16 + lr) * 128 + k4 * 32 + lg * 8];
      bf16x8 b1 = *(const bf16x8*)&Wt[kc * 16384 + ((cf0 + 1) * 16 + lr) * 128 + k4 * 32 + lg * 8];
      acc0 = __builtin_amdgcn_mfma_f32_16x16x32_bf16(a, b0, acc0, 0, 0, 0);
      acc1 = __builtin_amdgcn_mfma_f32_16x16x32_bf16(a, b1, acc1, 0, 0, 0);
    }
  }

#pragma unroll
  for (int r = 0; r < 4; ++r) {
    int row = node0 + lg * 4 + r;
    if (row < n) {
      out[(size_t)row * H + cf0 * 16 + lr] = acc0[r];
      out[(size_t)row * H + (cf0 + 1) * 16 + lr] = acc1[r];
    }
  }
}

// ---------------------------------------------------------------------------
extern "C" void kernel_launch(void* const* d_in, const int* in_sizes, int n_in,
                              void* d_out, int out_size, void* d_ws, size_t ws_size,
                              hipStream_t stream) {
  const float* X = (const float*)d_in[0];
  const int* edges[4] = {(const int*)d_in[1], (const int*)d_in[2],
                         (const int*)d_in[3], (const int*)d_in[4]};
  const float* Wk[4] = {(const float*)d_in[5], (const float*)d_in[6],
                        (const float*)d_in[7], (const float*)d_in[8]};
  float* out = (float*)d_out;

  int n = in_sizes[0] / H;
  int nE[4];
  int tot = 0;
  for (int k = 0; k < 4; ++k) {
    nE[k] = in_sizes[1 + k] / 2;
    tot += nE[k];
  }
  int c1 = nE[0], c2 = c1 + nE[1], c3 = c2 + nE[2];
  int nbin = (n + BNODES - 1) >> BSH;   // dst buckets
  int nblk = (tot + EPB - 1) / EPB;     // partition blocks

  // workspace layout
  char* ws = (char*)d_ws;
  size_t off = 0;
  auto take = [&](size_t bytes) -> char* {
    char* p = ws + off;
    off = (off + bytes + 255) & ~(size_t)255;
    return p;
  };
  ushort* Wt = (ushort*)take(4 * 128 * 128 * sizeof(ushort));
  uint* Xb = (uint*)take((size_t)n * H * sizeof(ushort));
  int* hb = (int*)take((size_t)nblk * nbin * sizeof(int));
  int* btot = (int*)take((size_t)nbin * sizeof(int));
  int* binbase = (int*)take((size_t)(nbin + 1) * sizeof(int));
  int* rp4 = (int*)take(((size_t)nbin * SEGB + 1) * sizeof(int));
  uint* part = (uint*)take((size_t)tot * sizeof(uint));
  int* col_idx = (int*)take((size_t)tot * sizeof(int));

  const int* s0 = edges[0];
  const int* d0 = edges[0] + nE[0];
  const int* s1 = edges[1];
  const int* d1 = edges[1] + nE[1];
  const int* s2 = edges[2];
  const int* d2 = edges[2] + nE[2];
  const int* s3 = edges[3];
  const int* d3 = edges[3] + nE[3];

  conv_prep<<<(n * 32 + 255) / 256, 256, 0, stream>>>(
      (const float4*)X, (uint2*)Xb, n * 32, Wk[0], Wk[1], Wk[2], Wk[3], Wt);

  part_count<<<nblk, 256, 0, stream>>>(d0, d1, d2, d3, c1, c2, c3, tot, nbin, hb);
  part_scanA<<<nbin, 256, 0, stream>>>(hb, nblk, nbin, btot);
  part_scanB<<<1, 512, 0, stream>>>(btot, binbase, nbin);
  part_scatter<<<nblk, 256, 0, stream>>>(d0, d1, d2, d3, s0, s1, s2, s3,
                                         c1, c2, c3, tot, nbin, hb, binbase, part);
  build_bucket<<<nbin, 1024, 0, stream>>>(part, binbase, rp4, col_idx);

  gg<<<(n + 15) / 16, 256, 0, stream>>>(Xb, rp4, col_idx, Wt, out, n);
}